// Round 6
// baseline (313.247 us; speedup 1.0000x reference)
//
#include <hip/hip_runtime.h>

typedef __bf16 bf16_t;
typedef bf16_t bf16x8 __attribute__((ext_vector_type(8)));
typedef float f32x4 __attribute__((ext_vector_type(4)));
typedef unsigned short u16;
typedef unsigned int u32;

#define E_TOT 524288
#define MT 128
#define NBLK (E_TOT / MT)   // 4096

__device__ __forceinline__ u16 f2bf(float f) {
  u32 u = __builtin_bit_cast(u32, f);
  u += 0x7FFFu + ((u >> 16) & 1u);
  return (u16)(u >> 16);
}

__device__ __forceinline__ bf16x8 pack8(f32x4 a, f32x4 b) {
  bf16x8 p;
  p[0] = (bf16_t)a[0]; p[1] = (bf16_t)a[1]; p[2] = (bf16_t)a[2]; p[3] = (bf16_t)a[3];
  p[4] = (bf16_t)b[0]; p[5] = (bf16_t)b[1]; p[6] = (bf16_t)b[2]; p[7] = (bf16_t)b[3];
  return p;
}

__device__ __forceinline__ void gload_lds16(const void* g, void* l) {
  __builtin_amdgcn_global_load_lds(
      (const __attribute__((address_space(1))) u32*)g,
      (__attribute__((address_space(3))) u32*)l, 16, 0, 0);
}

// W1 [384][256] f32 -> chunked linear bf16: 12 chunks of BK=32.
// 16-B unit U = c*1024 + n*4 + j holds W1^T[n][c*32 + j*8 .. +8)
__global__ void prep_w1tc(const float* __restrict__ W1, u16* __restrict__ W1Tc) {
  int t = blockIdx.x * 256 + threadIdx.x;  // 0..98303
  if (t < 384 * 256) {
    int U = t >> 3, e = t & 7;
    int c = U >> 10, rem = U & 1023;
    int n = rem >> 2, j = rem & 3;
    int k = c * 32 + j * 8 + e;
    W1Tc[t] = f2bf(W1[k * 256 + n]);
  }
}

// W2 [256][64] f32 -> W2T [64][256] bf16 row-major (epilogue register B-frags)
__global__ void prep_w2t(const float* __restrict__ W2, u16* __restrict__ W2T) {
  int t = blockIdx.x * 256 + threadIdx.x;
  if (t < 64 * 256) {
    int n = t / 256, k = t % 256;
    W2T[t] = f2bf(W2[k * 64 + n]);
  }
}

// Fused: x = [src|dest|edge|u[batch]] (E x 384); h = relu(x@W1+b1); out = h@W2+b2
__global__ void __launch_bounds__(512) edge_fused(
    const float* __restrict__ src, const float* __restrict__ dst,
    const float* __restrict__ ea, const float* __restrict__ u,
    const int* __restrict__ batch, const u16* __restrict__ W1Tc,
    const float* __restrict__ b1, const u16* __restrict__ W2T,
    const float* __restrict__ b2, float* __restrict__ out)
{
  // 65536 B LDS: A f32 triple-buf 3x16KB @0, W bf16 single-buf 16KB @49152.
  // Epilogue: Hs[128][256] bf16 (64KB) overlays everything.
  __shared__ __align__(16) u16 smem[32768];
  float* Af = (float*)smem;        // 3 * 4096 f32
  u16*   Wb = smem + 24576;        // 8192 u16
  u16*   Hs = smem;                // 32768 u16

  const int t    = threadIdx.x;
  const int wid  = t >> 6;
  const int lane = t & 63;
  const int lr   = lane & 15;
  const int lg   = lane >> 4;
  const int wr   = wid >> 2;      // 0..1 : 64-row half
  const int wc   = wid & 3;       // 0..3 : 64-col slice of HIDDEN
  const int e0   = blockIdx.x * MT;

  // A-glds: wave wid stages rows [16*wid, 16*wid+16) per chunk, 2 glds of 8 rows.
  const int rA  = wid * 16 + (lane >> 3);      // rows for glds 2*wid
  const int usw = (lane & 7) ^ ((lane >> 3) & 7);  // swizzled source 16B-unit
  const float* psrcA = src + (size_t)(e0 + rA) * 128 + usw * 4;
  const float* pdstA = dst + (size_t)(e0 + rA) * 128 + usw * 4;
  const float* peaA  = ea  + (size_t)(e0 + rA) * 64  + usw * 4;
  const float* puA   = u + (size_t)batch[e0 + rA]     * 64 + usw * 4;
  const float* puB   = u + (size_t)batch[e0 + rA + 8] * 64 + usw * 4;

  auto issueA = [&](int c) {
    const float *qa, *qb; int off;
    if (c < 4)       { qa = psrcA; qb = qa + 1024; off = c * 32; }        // rows +8 = +1024 f32
    else if (c < 8)  { qa = pdstA; qb = qa + 1024; off = (c - 4) * 32; }
    else if (c < 10) { qa = peaA;  qb = qa + 512;  off = (c - 8) * 32; }
    else             { qa = puA;   qb = puB;       off = (c - 10) * 32; }
    float* base = Af + (c % 3) * 4096 + wid * 512;   // 2 glds x 256 f32, wave-uniform
    gload_lds16(qa + off, base);
    gload_lds16(qb + off, base + 256);
  };
  auto issueW = [&](int c) {
    u16* base = Wb + wid * 1024;                     // 2 glds x 512 u16
    gload_lds16(W1Tc + ((size_t)c * 1024 + wid * 128 + lane) * 8, base);
    gload_lds16(W1Tc + ((size_t)c * 1024 + wid * 128 + 64 + lane) * 8, base + 512);
  };

  // prologue: per wave A0(2), W0(2), A1(2) -> steady vmcnt(2) from iter 0
  issueA(0);
  issueW(0);
  issueA(1);

  f32x4 acc[4][4];
  #pragma unroll
  for (int i = 0; i < 4; ++i)
    #pragma unroll
    for (int j = 0; j < 4; ++j)
      acc[i][j] = (f32x4){0.f, 0.f, 0.f, 0.f};

  // ---- K loop: 12 chunks of 32 ----
  #pragma unroll
  for (int kb = 0; kb < 12; ++kb) {
    // wait for chunk kb (A+W); chunk kb+1's A (2 newest glds) stays in flight
    if (kb < 11) asm volatile("s_waitcnt vmcnt(2)" ::: "memory");
    else         asm volatile("s_waitcnt vmcnt(0)" ::: "memory");
    __builtin_amdgcn_sched_barrier(0);
    __builtin_amdgcn_s_barrier();

    const float* Ac = Af + (kb % 3) * 4096;

    __builtin_amdgcn_s_setprio(1);
    bf16x8 af[4];
    #pragma unroll
    for (int mf = 0; mf < 4; ++mf) {
      int row = wr * 64 + mf * 16 + lr;
      int b16 = row * 8;
      f32x4 v0 = *(const f32x4*)(Ac + (size_t)(b16 + ((2 * lg)     ^ (row & 7))) * 4);
      f32x4 v1 = *(const f32x4*)(Ac + (size_t)(b16 + ((2 * lg + 1) ^ (row & 7))) * 4);
      af[mf] = pack8(v0, v1);
    }
    #pragma unroll
    for (int nf = 0; nf < 4; ++nf) {
      int n = wc * 64 + nf * 16 + lr;
      bf16x8 bfr = *(const bf16x8*)&Wb[n * 32 + lg * 8];
      #pragma unroll
      for (int mf = 0; mf < 4; ++mf)
        acc[mf][nf] = __builtin_amdgcn_mfma_f32_16x16x32_bf16(af[mf], bfr, acc[mf][nf], 0, 0, 0);
    }
    __builtin_amdgcn_s_setprio(0);
    __builtin_amdgcn_s_barrier();   // all waves' reads of chunk kb done

    // post-barrier staging: W(kb+1) into the single W buffer, A(kb+2) into free A buf
    if (kb < 11) issueW(kb + 1);
    if (kb < 10) issueA(kb + 2);
  }

  // ---- h = relu(acc + b1) -> Hs [128][256] swizzled (overlays A/W bufs) ----
  float bias1[4];
  #pragma unroll
  for (int nf = 0; nf < 4; ++nf) bias1[nf] = b1[wc * 64 + nf * 16 + lr];
  #pragma unroll
  for (int mf = 0; mf < 4; ++mf)
    #pragma unroll
    for (int nf = 0; nf < 4; ++nf)
      #pragma unroll
      for (int rr = 0; rr < 4; ++rr) {
        int row = wr * 64 + mf * 16 + lg * 4 + rr;
        int col = wc * 64 + nf * 16 + lr;
        float v = fmaxf(acc[mf][nf][rr] + bias1[nf], 0.f);
        Hs[row * 256 + ((((col >> 3) ^ (row & 7)) << 3) | (col & 7))] = f2bf(v);
      }
  __syncthreads();

  // ---- layer 2: out[128][64] = Hs @ W2; B-frags in registers from L2 ----
  const int wc2 = wid & 3;
  const int wr2 = wid >> 2;
  const int n2  = wc2 * 16 + lr;
  bf16x8 b2f[8];
  #pragma unroll
  for (int ks = 0; ks < 8; ++ks)
    b2f[ks] = *(const bf16x8*)(W2T + n2 * 256 + ks * 32 + lg * 8);
  const float bb = b2[n2];

  f32x4 acc2[4];
  #pragma unroll
  for (int mf = 0; mf < 4; ++mf) acc2[mf] = (f32x4){0.f, 0.f, 0.f, 0.f};
  #pragma unroll
  for (int ks = 0; ks < 8; ++ks) {
    #pragma unroll
    for (int mf = 0; mf < 4; ++mf) {
      int row = wr2 * 64 + mf * 16 + lr;
      bf16x8 a = *(const bf16x8*)&Hs[(row * 32 + ((ks * 4 + lg) ^ (row & 7))) * 8];
      acc2[mf] = __builtin_amdgcn_mfma_f32_16x16x32_bf16(a, b2f[ks], acc2[mf], 0, 0, 0);
    }
  }

  #pragma unroll
  for (int mf = 0; mf < 4; ++mf)
    #pragma unroll
    for (int rr = 0; rr < 4; ++rr) {
      int row = e0 + wr2 * 64 + mf * 16 + lg * 4 + rr;
      out[(size_t)row * 64 + n2] = acc2[mf][rr] + bb;
    }
}

extern "C" void kernel_launch(void* const* d_in, const int* in_sizes, int n_in,
                              void* d_out, int out_size, void* d_ws, size_t ws_size,
                              hipStream_t stream) {
  const float* src  = (const float*)d_in[0];
  const float* dst  = (const float*)d_in[1];
  const float* ea   = (const float*)d_in[2];
  const float* u    = (const float*)d_in[3];
  const int* batch  = (const int*)d_in[4];
  const float* W1   = (const float*)d_in[5];
  const float* b1   = (const float*)d_in[6];
  const float* W2   = (const float*)d_in[7];
  const float* b2   = (const float*)d_in[8];
  float* out = (float*)d_out;

  u16* W1Tc = (u16*)d_ws;            // 12 chunks x 8192 u16 (chunked linear W1^T)
  u16* W2T  = W1Tc + 384 * 256;      // 64*256 u16

  prep_w1tc<<<(384 * 256 + 255) / 256, 256, 0, stream>>>(W1, W1Tc);
  prep_w2t<<<(64 * 256 + 255) / 256, 256, 0, stream>>>(W2, W2T);
  edge_fused<<<NBLK, 512, 0, stream>>>(src, dst, ea, u, batch, W1Tc, b1, W2T, b2, out);
}

// Round 7
// 235.155 us; speedup vs baseline: 1.3321x; 1.3321x over previous
//
#include <hip/hip_runtime.h>

typedef __bf16 bf16_t;
typedef bf16_t bf16x8 __attribute__((ext_vector_type(8)));
typedef float f32x4 __attribute__((ext_vector_type(4)));
typedef unsigned short u16;
typedef unsigned int u32;

#define E_TOT 524288
#define MT 64
#define NBLK (E_TOT / MT)   // 8192

__device__ __forceinline__ u16 f2bf(float f) {
  u32 u = __builtin_bit_cast(u32, f);
  u += 0x7FFFu + ((u >> 16) & 1u);
  return (u16)(u >> 16);
}

__device__ __forceinline__ bf16x8 pack8(f32x4 a, f32x4 b) {
  bf16x8 p;
  p[0] = (bf16_t)a[0]; p[1] = (bf16_t)a[1]; p[2] = (bf16_t)a[2]; p[3] = (bf16_t)a[3];
  p[4] = (bf16_t)b[0]; p[5] = (bf16_t)b[1]; p[6] = (bf16_t)b[2]; p[7] = (bf16_t)b[3];
  return p;
}

__device__ __forceinline__ void gload_lds16(const void* g, void* l) {
  __builtin_amdgcn_global_load_lds(
      (const __attribute__((address_space(1))) u32*)g,
      (__attribute__((address_space(3))) u32*)l, 16, 0, 0);
}

// W1 [384][256] f32 -> 12 chunks (BK=32) of bank-swizzled W1^T bf16.
// 16-B unit U = c*1024 + n*4 + j holds W1^T[n][c*32 + ((j^((n>>1)&3))*8) .. +8)
__global__ void prep_w1tc(const float* __restrict__ W1, u16* __restrict__ W1Tc) {
  int t = blockIdx.x * 256 + threadIdx.x;  // 0..98303
  if (t < 384 * 256) {
    int U = t >> 3, e = t & 7;
    int c = U >> 10, rem = U & 1023;
    int n = rem >> 2, j = rem & 3;
    int k = c * 32 + ((j ^ ((n >> 1) & 3)) << 3) + e;
    W1Tc[t] = f2bf(W1[k * 256 + n]);
  }
}

// W2 [256][64] f32 -> W2T [64][256] bf16 row-major (epilogue register B-frags)
__global__ void prep_w2t(const float* __restrict__ W2, u16* __restrict__ W2T) {
  int t = blockIdx.x * 256 + threadIdx.x;
  if (t < 64 * 256) {
    int n = t / 256, k = t % 256;
    W2T[t] = f2bf(W2[k * 64 + n]);
  }
}

// Fused: x = [src|dest|edge|u[batch]] (E x 384); h = relu(x@W1+b1); out = h@W2+b2
__global__ void __launch_bounds__(256) edge_fused(
    const float* __restrict__ src, const float* __restrict__ dst,
    const float* __restrict__ ea, const float* __restrict__ u,
    const int* __restrict__ batch, const u16* __restrict__ W1Tc,
    const float* __restrict__ b1, const u16* __restrict__ W2T,
    const float* __restrict__ b2, float* __restrict__ out)
{
  // 40960 B LDS: As 2 x 2048 u16 @0 (8KB), Wb 2 x 8192 u16 @4096 (32KB).
  // Epilogue: Hs[64][256] (16384 u16, 32KB) overlays everything.
  __shared__ __align__(16) u16 smem[20480];
  u16* As = smem;            // double-buffered A (bf16, swizzled)
  u16* Wb = smem + 4096;     // double-buffered W chunk
  u16* Hs = smem;

  const int t    = threadIdx.x;
  const int wid  = t >> 6;
  const int lane = t & 63;
  const int lr   = lane & 15;
  const int lg   = lane >> 4;
  const int e0   = blockIdx.x * MT;
  const int r    = t >> 2;        // A row owned by this thread (0..63)
  const int jcol = t & 3;         // 16B-unit within 32-col chunk
  const int bidx = batch[e0 + r];
  // A ds_write unit (bank-swizzled, 2-way max)
  const int wunit = r * 4 + (jcol ^ ((r >> 1) & 3));

  auto loadA = [&](int c, f32x4* ra) {
    const float* p;
    if (c < 4)       p = src + (size_t)(e0 + r) * 128 + c * 32 + jcol * 8;
    else if (c < 8)  p = dst + (size_t)(e0 + r) * 128 + (c - 4) * 32 + jcol * 8;
    else if (c < 10) p = ea + (size_t)(e0 + r) * 64 + (c - 8) * 32 + jcol * 8;
    else             p = u + (size_t)bidx * 64 + (c - 10) * 32 + jcol * 8;
    ra[0] = *(const f32x4*)p;
    ra[1] = *(const f32x4*)(p + 4);
  };
  auto issueW = [&](int c, u16* Wn) {
    #pragma unroll
    for (int g = 0; g < 4; ++g) {
      int ub = wid * 256 + g * 64;   // wave-uniform 16B-unit base
      gload_lds16(W1Tc + ((size_t)c * 1024 + ub + lane) * 8, Wn + ub * 8);
    }
  };

  // prologue: A0, W0, A1, W1 in flight
  f32x4 ra[2], rb[2];
  loadA(0, ra);
  issueW(0, Wb);
  loadA(1, rb);
  issueW(1, Wb + 8192);

  f32x4 acc[4][4];
  #pragma unroll
  for (int i = 0; i < 4; ++i)
    #pragma unroll
    for (int j = 0; j < 4; ++j)
      acc[i][j] = (f32x4){0.f, 0.f, 0.f, 0.f};

  // ---- K loop: 12 chunks of 32 ----
  #pragma unroll
  for (int kb = 0; kb < 12; ++kb) {
    f32x4* rc = (kb & 1) ? rb : ra;
    u16* Ab = As + (kb & 1) * 2048;
    u16* Wc = Wb + (kb & 1) * 8192;

    // pack + write A(kb) (compiler waits its own 2 loads; glds stay in flight)
    *(bf16x8*)&Ab[wunit * 8] = pack8(rc[0], rc[1]);
    // refill this register pair with A(kb+2)
    if (kb <= 9) loadA(kb + 2, rc);

    // publish A(kb) + W(kb); newer in flight: W(kb+1)4 + gA(kb+1)2 + gA(kb+2)2
    if (kb <= 9)      asm volatile("s_waitcnt vmcnt(8) lgkmcnt(0)" ::: "memory");
    else if (kb == 10) asm volatile("s_waitcnt vmcnt(6) lgkmcnt(0)" ::: "memory");
    else               asm volatile("s_waitcnt vmcnt(0) lgkmcnt(0)" ::: "memory");
    __builtin_amdgcn_sched_barrier(0);
    __builtin_amdgcn_s_barrier();

    __builtin_amdgcn_s_setprio(1);
    bf16x8 af[4];
    #pragma unroll
    for (int mf = 0; mf < 4; ++mf) {
      int row = mf * 16 + lr;
      af[mf] = *(const bf16x8*)&Ab[(row * 4 + (lg ^ ((row >> 1) & 3))) * 8];
    }
    #pragma unroll
    for (int nf = 0; nf < 4; ++nf) {
      int n = wid * 64 + nf * 16 + lr;
      bf16x8 bfr = *(const bf16x8*)&Wc[(n * 4 + (lg ^ ((n >> 1) & 3))) * 8];
      #pragma unroll
      for (int mf = 0; mf < 4; ++mf)
        acc[mf][nf] = __builtin_amdgcn_mfma_f32_16x16x32_bf16(af[mf], bfr, acc[mf][nf], 0, 0, 0);
    }
    __builtin_amdgcn_s_setprio(0);
    __builtin_amdgcn_s_barrier();   // all waves done reading Ab/Wc

    // stage W(kb+2) into the just-freed Wc
    if (kb <= 9) issueW(kb + 2, Wc);
  }

  // ---- h = relu(acc + b1) -> Hs [64][256] swizzled (overlays As/Wb) ----
  float bias1[4];
  #pragma unroll
  for (int nf = 0; nf < 4; ++nf) bias1[nf] = b1[wid * 64 + nf * 16 + lr];
  #pragma unroll
  for (int mf = 0; mf < 4; ++mf)
    #pragma unroll
    for (int nf = 0; nf < 4; ++nf)
      #pragma unroll
      for (int rr = 0; rr < 4; ++rr) {
        int row = mf * 16 + lg * 4 + rr;
        int col = wid * 64 + nf * 16 + lr;
        float v = fmaxf(acc[mf][nf][rr] + bias1[nf], 0.f);
        Hs[row * 256 + ((((col >> 3) ^ (row & 7)) << 3) | (col & 7))] = f2bf(v);
      }
  __syncthreads();

  // ---- layer 2: out[64][64] = Hs @ W2; B-frags in registers from L2 ----
  const int n2 = wid * 16 + lr;
  bf16x8 b2f[8];
  #pragma unroll
  for (int ks = 0; ks < 8; ++ks)
    b2f[ks] = *(const bf16x8*)(W2T + n2 * 256 + ks * 32 + lg * 8);
  const float bb = b2[n2];

  f32x4 acc2[4];
  #pragma unroll
  for (int mf = 0; mf < 4; ++mf) acc2[mf] = (f32x4){0.f, 0.f, 0.f, 0.f};
  #pragma unroll
  for (int ks = 0; ks < 8; ++ks) {
    #pragma unroll
    for (int mf = 0; mf < 4; ++mf) {
      int row = mf * 16 + lr;
      bf16x8 a = *(const bf16x8*)&Hs[row * 256 + (((ks * 4 + lg) ^ (row & 7)) << 3)];
      acc2[mf] = __builtin_amdgcn_mfma_f32_16x16x32_bf16(a, b2f[ks], acc2[mf], 0, 0, 0);
    }
  }

  #pragma unroll
  for (int mf = 0; mf < 4; ++mf)
    #pragma unroll
    for (int rr = 0; rr < 4; ++rr) {
      int row = e0 + mf * 16 + lg * 4 + rr;
      out[(size_t)row * 64 + n2] = acc2[mf][rr] + bb;
    }
}

extern "C" void kernel_launch(void* const* d_in, const int* in_sizes, int n_in,
                              void* d_out, int out_size, void* d_ws, size_t ws_size,
                              hipStream_t stream) {
  const float* src  = (const float*)d_in[0];
  const float* dst  = (const float*)d_in[1];
  const float* ea   = (const float*)d_in[2];
  const float* u    = (const float*)d_in[3];
  const int* batch  = (const int*)d_in[4];
  const float* W1   = (const float*)d_in[5];
  const float* b1   = (const float*)d_in[6];
  const float* W2   = (const float*)d_in[7];
  const float* b2   = (const float*)d_in[8];
  float* out = (float*)d_out;

  u16* W1Tc = (u16*)d_ws;            // 12 chunks x 1024 16B-units (swizzled W1^T)
  u16* W2T  = W1Tc + 384 * 256;      // 64*256 u16

  prep_w1tc<<<(384 * 256 + 255) / 256, 256, 0, stream>>>(W1, W1Tc);
  prep_w2t<<<(64 * 256 + 255) / 256, 256, 0, stream>>>(W2, W2T);
  edge_fused<<<NBLK, 256, 0, stream>>>(src, dst, ea, u, batch, W1Tc, b1, W2T, b2, out);
}

// Round 8
// 234.702 us; speedup vs baseline: 1.3347x; 1.0019x over previous
//
#include <hip/hip_runtime.h>

typedef __bf16 bf16_t;
typedef bf16_t bf16x8 __attribute__((ext_vector_type(8)));
typedef bf16_t bf16x4 __attribute__((ext_vector_type(4)));
typedef float f32x4 __attribute__((ext_vector_type(4)));
typedef unsigned short u16;
typedef unsigned int u32;

#define E_TOT 524288
#define MT 64
#define NBLK (E_TOT / MT)   // 8192

__device__ __forceinline__ u16 f2bf(float f) {
  u32 u = __builtin_bit_cast(u32, f);
  u += 0x7FFFu + ((u >> 16) & 1u);
  return (u16)(u >> 16);
}

__device__ __forceinline__ bf16x8 pack8(f32x4 a, f32x4 b) {
  bf16x8 p;
  p[0] = (bf16_t)a[0]; p[1] = (bf16_t)a[1]; p[2] = (bf16_t)a[2]; p[3] = (bf16_t)a[3];
  p[4] = (bf16_t)b[0]; p[5] = (bf16_t)b[1]; p[6] = (bf16_t)b[2]; p[7] = (bf16_t)b[3];
  return p;
}

// W1F frag-ordered: idx = (((kb*4+wc)*4+nf)*64+l)*8+e
//   holds W1^T[n=wc*64+nf*16+(l&15)][k=kb*32+(l>>4)*8+e] = W1[k*256+n]
__global__ void prep_w1f(const float* __restrict__ W1, u16* __restrict__ W1F) {
  int t = blockIdx.x * 256 + threadIdx.x;  // 0..98303
  if (t < 98304) {
    int e  = t & 7;
    int l  = (t >> 3) & 63;
    int nf = (t >> 9) & 3;
    int wc = (t >> 11) & 3;
    int kb = t >> 13;
    int n = wc * 64 + nf * 16 + (l & 15);
    int k = kb * 32 + ((l >> 4) << 3) + e;
    W1F[t] = f2bf(W1[k * 256 + n]);
  }
}

// W2F frag-ordered: idx = ((ks*4+n2f)*64+l)*8+e
//   holds W2^T[n2=n2f*16+(l&15)][k=ks*32+(l>>4)*8+e] = W2[k*64+n2]
__global__ void prep_w2f(const float* __restrict__ W2, u16* __restrict__ W2F) {
  int t = blockIdx.x * 256 + threadIdx.x;  // 0..16383
  if (t < 16384) {
    int e   = t & 7;
    int l   = (t >> 3) & 63;
    int n2f = (t >> 9) & 3;
    int ks  = t >> 11;
    int n2 = n2f * 16 + (l & 15);
    int k  = ks * 32 + ((l >> 4) << 3) + e;
    W2F[t] = f2bf(W2[k * 64 + n2]);
  }
}

// Fused: x = [src|dest|edge|u[batch]] (E x 384); h = relu(x@W1+b1); out = h@W2+b2
// Swapped layer-1: acc = mfma(W_frag, x_frag) -> holds h^T fragments.
__global__ void __launch_bounds__(256) edge_fused(
    const float* __restrict__ src, const float* __restrict__ dst,
    const float* __restrict__ ea, const float* __restrict__ u,
    const int* __restrict__ batch, const u16* __restrict__ W1F,
    const float* __restrict__ b1, const u16* __restrict__ W2F,
    const float* __restrict__ b2, float* __restrict__ out)
{
  // 32 KB LDS: As dbuf 2x2048 u16 (8 KB) during K-loop; Hs[64][256] bf16 overlays.
  __shared__ __align__(16) u16 smem[16384];
  u16* As = smem;
  u16* Hs = smem;

  const int t    = threadIdx.x;
  const int wid  = t >> 6;
  const int lane = t & 63;
  const int lr   = lane & 15;
  const int lg   = lane >> 4;
  const int e0   = blockIdx.x * MT;
  const int r    = t >> 2;        // A row owned by this thread
  const int jcol = t & 3;         // 16B-unit within 32-col chunk
  const int bidx = batch[e0 + r];
  const int wunit = r * 4 + (jcol ^ ((r >> 1) & 3));   // A write unit (2-way max)

  auto loadA = [&](int c, f32x4* ra) {
    const float* p;
    if (c < 4)       p = src + (size_t)(e0 + r) * 128 + c * 32 + jcol * 8;
    else if (c < 8)  p = dst + (size_t)(e0 + r) * 128 + (c - 4) * 32 + jcol * 8;
    else if (c < 10) p = ea + (size_t)(e0 + r) * 64 + (c - 8) * 32 + jcol * 8;
    else             p = u + (size_t)bidx * 64 + (c - 10) * 32 + jcol * 8;
    ra[0] = *(const f32x4*)p;
    ra[1] = *(const f32x4*)(p + 4);
  };
  auto loadW1 = [&](int c, bf16x8* wf) {
    const u16* p = W1F + ((size_t)(c * 4 + wid) * 4) * 512 + lane * 8;
    wf[0] = *(const bf16x8*)(p);
    wf[1] = *(const bf16x8*)(p + 512);
    wf[2] = *(const bf16x8*)(p + 1024);
    wf[3] = *(const bf16x8*)(p + 1536);
  };

  // prologue: A chunks 0,1 + W chunks 0,1 in flight
  f32x4 ra[2], rb[2];
  bf16x8 wA[4], wB[4];
  loadA(0, ra);
  loadW1(0, wA);
  loadA(1, rb);
  loadW1(1, wB);

  f32x4 acc[4][4];   // [nf][mf] : h^T frags (n per (lg,rr), x-row per lr)
  #pragma unroll
  for (int i = 0; i < 4; ++i)
    #pragma unroll
    for (int j = 0; j < 4; ++j)
      acc[i][j] = (f32x4){0.f, 0.f, 0.f, 0.f};

  // ---- K loop: 12 chunks of 32; single barrier per chunk ----
  #pragma unroll
  for (int kb = 0; kb < 12; ++kb) {
    f32x4*  rc = (kb & 1) ? rb : ra;
    bf16x8* wc_ = (kb & 1) ? wB : wA;
    u16* Ab = As + (kb & 1) * 2048;

    // publish A(kb) (compiler waits only rc's 2 loads), refill with A(kb+2)
    *(bf16x8*)&Ab[wunit * 8] = pack8(rc[0], rc[1]);
    if (kb <= 9) loadA(kb + 2, rc);
    __syncthreads();

    __builtin_amdgcn_s_setprio(1);
    bf16x8 af[4];
    #pragma unroll
    for (int mf = 0; mf < 4; ++mf) {
      int row = mf * 16 + lr;
      af[mf] = *(const bf16x8*)&Ab[(row * 4 + (lg ^ ((row >> 1) & 3))) * 8];
    }
    #pragma unroll
    for (int nf = 0; nf < 4; ++nf)
      #pragma unroll
      for (int mf = 0; mf < 4; ++mf)
        acc[nf][mf] = __builtin_amdgcn_mfma_f32_16x16x32_bf16(wc_[nf], af[mf], acc[nf][mf], 0, 0, 0);
    __builtin_amdgcn_s_setprio(0);

    // refill W regs with chunk kb+2 (ordered after last use via register dep)
    if (kb <= 9) loadW1(kb + 2, wc_);
  }
  __syncthreads();  // last As reads done before Hs overlay

  // ---- h^T -> Hs[64 rows][256 hid] bf16, b64 writes, XOR swizzle on 8B units ----
  #pragma unroll
  for (int nf = 0; nf < 4; ++nf) {
    f32x4 b1v = *(const f32x4*)(b1 + wid * 64 + nf * 16 + lg * 4);
    #pragma unroll
    for (int mf = 0; mf < 4; ++mf) {
      int row = mf * 16 + lr;
      bf16x4 hb;
      #pragma unroll
      for (int rr = 0; rr < 4; ++rr)
        hb[rr] = (bf16_t)fmaxf(acc[nf][mf][rr] + b1v[rr], 0.f);
      int uu = (wid * 4 + nf) * 4 + lg;          // 8B-unit = hid>>2
      int up = uu ^ ((row & 3) << 3);
      *(bf16x4*)&Hs[row * 256 + up * 4] = hb;
    }
  }
  __syncthreads();

  // ---- layer 2: out^T frags = mfma(W2_frag, h_frag); W2 from L1/L2 ----
  const int row2 = wid * 16 + lr;
  f32x4 d2[4];
  #pragma unroll
  for (int i = 0; i < 4; ++i) d2[i] = (f32x4){0.f, 0.f, 0.f, 0.f};
  #pragma unroll
  for (int ks = 0; ks < 8; ++ks) {
    int uu = ks * 8 + lg * 2;
    int up = uu ^ ((row2 & 3) << 3);
    bf16x8 a2 = *(const bf16x8*)&Hs[row2 * 256 + up * 4];
    const u16* q = W2F + (size_t)ks * 2048 + lane * 8;
    #pragma unroll
    for (int n2f = 0; n2f < 4; ++n2f)
      d2[n2f] = __builtin_amdgcn_mfma_f32_16x16x32_bf16(
          *(const bf16x8*)(q + n2f * 512), a2, d2[n2f], 0, 0, 0);
  }

  // ---- epilogue store: lane holds out[row2][n2f*16+lg*4+rr] ----
  #pragma unroll
  for (int n2f = 0; n2f < 4; ++n2f) {
    f32x4 b2v = *(const f32x4*)(b2 + n2f * 16 + lg * 4);
    f32x4 ov = d2[n2f] + b2v;
    *(f32x4*)&out[(size_t)(e0 + row2) * 64 + n2f * 16 + lg * 4] = ov;
  }
}

extern "C" void kernel_launch(void* const* d_in, const int* in_sizes, int n_in,
                              void* d_out, int out_size, void* d_ws, size_t ws_size,
                              hipStream_t stream) {
  const float* src  = (const float*)d_in[0];
  const float* dst  = (const float*)d_in[1];
  const float* ea   = (const float*)d_in[2];
  const float* u    = (const float*)d_in[3];
  const int* batch  = (const int*)d_in[4];
  const float* W1   = (const float*)d_in[5];
  const float* b1   = (const float*)d_in[6];
  const float* W2   = (const float*)d_in[7];
  const float* b2   = (const float*)d_in[8];
  float* out = (float*)d_out;

  u16* W1F = (u16*)d_ws;          // 98304 u16 frag-ordered W1^T
  u16* W2F = W1F + 98304;         // 16384 u16 frag-ordered W2^T

  prep_w1f<<<384, 256, 0, stream>>>(W1, W1F);
  prep_w2f<<<64, 256, 0, stream>>>(W2, W2F);
  edge_fused<<<NBLK, 256, 0, stream>>>(src, dst, ea, u, batch, W1F, b1, W2F, b2, out);
}